// Round 8
// baseline (181.267 us; speedup 1.0000x reference)
//
#include <hip/hip_runtime.h>
#include <math.h>

typedef unsigned short ushort_t;
typedef __attribute__((ext_vector_type(8))) short bf16x8_t;
typedef __attribute__((ext_vector_type(4))) float f32x4_t;

// ---------------- split helpers ----------------
// Truncation split: hi = trunc16(v), lo = trunc16(v - hi); |err| <= 2^-16 |v|.
__device__ __forceinline__ void tsplit(float v, unsigned& h, unsigned& l) {
  unsigned u = __float_as_uint(v);
  h = u >> 16;
  float lo = v - __uint_as_float(u & 0xffff0000u);
  l = __float_as_uint(lo) >> 16;
}

// ---------------- prep: split x + transpose/split W1, W2 (one dispatch) ----
// Packed writes: each thread emits uint2 (4 ushorts) per plane.
__device__ __forceinline__ void transpose_tile(
    const float* __restrict__ W, ushort_t* __restrict__ Wh,
    ushort_t* __restrict__ Wl, int K, int N, int Kpad, int n0, int k0, int t) {
  __shared__ float sh[32][33];   // sh[n][k]
  const int tx = t & 31, ty = t >> 5;
#pragma unroll
  for (int i = 0; i < 4; ++i) {
    int k = k0 + i * 8 + ty;
    float v = (k < K && (n0 + tx) < N) ? W[(size_t)k * N + n0 + tx] : 0.f;
    sh[tx][i * 8 + ty] = v;
  }
  __syncthreads();
  const int nn = t >> 3;        // 0..31
  const int kq = t & 7;         // 0..7 -> 4 consecutive k
  unsigned h[4], l[4];
#pragma unroll
  for (int e = 0; e < 4; ++e) tsplit(sh[nn][kq * 4 + e], h[e], l[e]);
  size_t o = (size_t)(n0 + nn) * Kpad + k0 + kq * 4;
  uint2 ph, pl;
  ph.x = h[0] | (h[1] << 16); ph.y = h[2] | (h[3] << 16);
  pl.x = l[0] | (l[1] << 16); pl.y = l[2] | (l[3] << 16);
  *(uint2*)&Wh[o] = ph;
  *(uint2*)&Wl[o] = pl;
}

__global__ __launch_bounds__(256) void prep_kernel(
    const float* __restrict__ x, const float* __restrict__ W1,
    const float* __restrict__ W2,
    ushort_t* __restrict__ xh, ushort_t* __restrict__ xl,
    ushort_t* __restrict__ w1h, ushort_t* __restrict__ w1l,
    ushort_t* __restrict__ w2h, ushort_t* __restrict__ w2l) {
  const int bid = blockIdx.x;
  const int t = threadIdx.x;
  if (bid < 256) {
    // split x: 256*1024 floats, float4 per thread
    int i4 = bid * 256 + t;
    float4 v = ((const float4*)x)[i4];
    unsigned h0, l0, h1, l1, h2, l2, h3, l3;
    tsplit(v.x, h0, l0); tsplit(v.y, h1, l1);
    tsplit(v.z, h2, l2); tsplit(v.w, h3, l3);
    uint2 ph, pl;
    ph.x = h0 | (h1 << 16); ph.y = h2 | (h3 << 16);
    pl.x = l0 | (l1 << 16); pl.y = l2 | (l3 << 16);
    ((uint2*)xh)[i4] = ph;
    ((uint2*)xl)[i4] = pl;
  } else if (bid < 256 + 2048) {
    int tau = bid - 256;                 // W1: 64 n-tiles x 32 k-tiles
    transpose_tile(W1, w1h, w1l, 1024, 2047, 1024,
                   (tau & 63) * 32, (tau >> 6) * 32, t);
  } else {
    int tau = bid - 2304;                // W2: 128 n-tiles x 64 k-tiles
    transpose_tile(W2, w2h, w2l, 2047, 4095, 2048,
                   (tau & 127) * 32, (tau >> 7) * 32, t);
  }
}

// ---------------- fused 3-product split-bf16 MFMA GEMM (round-2 proven) ----
#define LSTR 40
__global__ __launch_bounds__(256) void gemm_fused_kernel(
    const ushort_t* __restrict__ Ah, const ushort_t* __restrict__ Al,
    const ushort_t* __restrict__ Bh, const ushort_t* __restrict__ Bl,
    float* __restrict__ part, int KA, int KH, int Npad) {
  __shared__ ushort_t lds[4][64 * LSTR];
  const int t = threadIdx.x;
  const int lane = t & 63;
  const int wv = t >> 6;
  const int lane15 = lane & 15;
  const int quad = lane >> 4;
  const int wm = wv >> 1, wn = wv & 1;
  const int m0 = blockIdx.y * 64;
  const int n0 = blockIdx.x * 64;
  const int ks = blockIdx.z;

  const ushort_t* src = (wv == 0) ? Ah : (wv == 1) ? Al : (wv == 2) ? Bh : Bl;
  const int rowBase = (wv < 2) ? m0 : n0;
  ushort_t* dst = &lds[wv][0];

  f32x4_t acc[2][2];
#pragma unroll
  for (int i = 0; i < 2; ++i)
#pragma unroll
    for (int j = 0; j < 2; ++j) acc[i][j] = (f32x4_t){0.f, 0.f, 0.f, 0.f};

  const int iters = KH >> 5;
  const int kbase = ks * KH;
  for (int kt = 0; kt < iters; ++kt) {
    const int k0 = kbase + (kt << 5);
#pragma unroll
    for (int q = 0; q < 4; ++q) {
      int r = q * 16 + (lane >> 2);
      int c = (lane & 3) * 8;
      *(int4*)&dst[r * LSTR + c] =
          *(const int4*)(src + (size_t)(rowBase + r) * KA + k0 + c);
    }
    __syncthreads();
    bf16x8_t afh[2], afl[2], bfh[2], bfl[2];
#pragma unroll
    for (int i = 0; i < 2; ++i) {
      int mr = wm * 32 + i * 16 + lane15;
      afh[i] = *(const bf16x8_t*)&lds[0][mr * LSTR + quad * 8];
      afl[i] = *(const bf16x8_t*)&lds[1][mr * LSTR + quad * 8];
      int nr = wn * 32 + i * 16 + lane15;
      bfh[i] = *(const bf16x8_t*)&lds[2][nr * LSTR + quad * 8];
      bfl[i] = *(const bf16x8_t*)&lds[3][nr * LSTR + quad * 8];
    }
#pragma unroll
    for (int i = 0; i < 2; ++i)
#pragma unroll
      for (int j = 0; j < 2; ++j) {
        acc[i][j] = __builtin_amdgcn_mfma_f32_16x16x32_bf16(
            afh[i], bfh[j], acc[i][j], 0, 0, 0);
        acc[i][j] = __builtin_amdgcn_mfma_f32_16x16x32_bf16(
            afh[i], bfl[j], acc[i][j], 0, 0, 0);
        acc[i][j] = __builtin_amdgcn_mfma_f32_16x16x32_bf16(
            afl[i], bfh[j], acc[i][j], 0, 0, 0);
      }
    __syncthreads();
  }
  float* pbase = part + (size_t)ks * 256 * Npad;
#pragma unroll
  for (int i = 0; i < 2; ++i)
#pragma unroll
    for (int j = 0; j < 2; ++j) {
      int row0 = m0 + wm * 32 + i * 16 + quad * 4;
      int col = n0 + wn * 32 + j * 16 + lane15;
#pragma unroll
      for (int reg = 0; reg < 4; ++reg)
        pbase[(size_t)(row0 + reg) * Npad + col] = acc[i][j][reg];
    }
}

// ---------------- GEMM2: 128m x 64n tile, split-K=4 ----------------
// A = hh/hl [256][2048] pre-split bf16; B = w2h/w2l [4096][2048] k-major.
// Waves: wm = wv>>1 over 64-row m halves (4 frags), wn = wv&1 over 32-col
// n halves (2 frags). 24 MFMAs per 12 ds_read_b128 per k-iter.
__global__ __launch_bounds__(256) void gemm2k_kernel(
    const ushort_t* __restrict__ Ah, const ushort_t* __restrict__ Al,
    const ushort_t* __restrict__ Bh, const ushort_t* __restrict__ Bl,
    float* __restrict__ part) {
  __shared__ ushort_t Ab[2][128 * LSTR];
  __shared__ ushort_t Bb[2][64 * LSTR];
  const int t = threadIdx.x;
  const int lane = t & 63;
  const int wv = t >> 6;
  const int l15 = lane & 15;
  const int quad = lane >> 4;
  const int wm = wv >> 1, wn = wv & 1;
  const int m0 = blockIdx.y * 128;
  const int n0 = blockIdx.x * 64;
  const int ks = blockIdx.z;

  f32x4_t acc[4][2];
#pragma unroll
  for (int i = 0; i < 4; ++i)
#pragma unroll
    for (int j = 0; j < 2; ++j) acc[i][j] = (f32x4_t){0.f, 0.f, 0.f, 0.f};

  for (int kt = 0; kt < 16; ++kt) {
    const int k0 = ks * 512 + kt * 32;
    if (wv < 2) {
      // A: 128 rows x 32 k, one plane per wave, 8 int4/lane
      const ushort_t* src = wv ? Al : Ah;
      ushort_t* dst = Ab[wv];
#pragma unroll
      for (int q = 0; q < 8; ++q) {
        int r = q * 16 + (lane >> 2);
        int c = (lane & 3) * 8;
        *(int4*)&dst[r * LSTR + c] =
            *(const int4*)(src + (size_t)(m0 + r) * 2048 + k0 + c);
      }
    } else {
      // B: 64 rows x 32 k, one plane per wave, 4 int4/lane
      const ushort_t* src = (wv == 3) ? Bl : Bh;
      ushort_t* dst = Bb[wv - 2];
#pragma unroll
      for (int q = 0; q < 4; ++q) {
        int r = q * 16 + (lane >> 2);
        int c = (lane & 3) * 8;
        *(int4*)&dst[r * LSTR + c] =
            *(const int4*)(src + (size_t)(n0 + r) * 2048 + k0 + c);
      }
    }
    __syncthreads();
    bf16x8_t bfh[2], bfl[2];
#pragma unroll
    for (int j = 0; j < 2; ++j) {
      int nr = wn * 32 + j * 16 + l15;
      bfh[j] = *(const bf16x8_t*)&Bb[0][nr * LSTR + quad * 8];
      bfl[j] = *(const bf16x8_t*)&Bb[1][nr * LSTR + quad * 8];
    }
#pragma unroll
    for (int i = 0; i < 4; ++i) {
      int mr = wm * 64 + i * 16 + l15;
      bf16x8_t afh = *(const bf16x8_t*)&Ab[0][mr * LSTR + quad * 8];
      bf16x8_t afl = *(const bf16x8_t*)&Ab[1][mr * LSTR + quad * 8];
#pragma unroll
      for (int j = 0; j < 2; ++j) {
        acc[i][j] = __builtin_amdgcn_mfma_f32_16x16x32_bf16(
            afh, bfh[j], acc[i][j], 0, 0, 0);
        acc[i][j] = __builtin_amdgcn_mfma_f32_16x16x32_bf16(
            afh, bfl[j], acc[i][j], 0, 0, 0);
        acc[i][j] = __builtin_amdgcn_mfma_f32_16x16x32_bf16(
            afl, bfh[j], acc[i][j], 0, 0, 0);
      }
    }
    __syncthreads();
  }
  float* pbase = part + (size_t)ks * 256 * 4096;
#pragma unroll
  for (int i = 0; i < 4; ++i)
#pragma unroll
    for (int j = 0; j < 2; ++j) {
      int row0 = m0 + wm * 64 + i * 16 + quad * 4;
      int col = n0 + wn * 32 + j * 16 + l15;
#pragma unroll
      for (int rg = 0; rg < 4; ++rg)
        pbase[(size_t)(row0 + rg) * 4096 + col] = acc[i][j][rg];
    }
}

// reduce split-K(2) partials + bias + silu, write split-bf16 h
__global__ __launch_bounds__(256) void reduce1_kernel(
    const float* __restrict__ p, const float* __restrict__ b1,
    ushort_t* __restrict__ hh, ushort_t* __restrict__ hl) {
  int idx = blockIdx.x * 256 + threadIdx.x;
  int n = idx & 2047;
  float v = p[idx] + p[idx + 256 * 2048];
  if (n < 2047) {
    v += b1[n];
    v = v / (1.f + expf(-v));
  } else {
    v = 0.f;
  }
  unsigned h, l;
  tsplit(v, h, l);
  hh[idx] = (ushort_t)h;
  hl[idx] = (ushort_t)l;
}

// ---------------- fallback fp32 GEMM (round-1, known-good) ----------------
#define TM 64
#define TN 64
#define TK 16
__global__ __launch_bounds__(256) void gemm_tiled(
    const float* __restrict__ X, const float* __restrict__ W,
    const float* __restrict__ bias, float* __restrict__ out,
    int M, int N, int K, int ldx, int ldw, int ldo, int doSilu, int padN)
{
  __shared__ float Xs[TK][TM + 4];
  __shared__ float Ws[TK][TN + 4];
  const int t = threadIdx.x;
  const int n0 = blockIdx.x * TN;
  const int m0 = blockIdx.y * TM;
  const int tr = t >> 4, tc = t & 15;
  float acc[4][4];
#pragma unroll
  for (int i = 0; i < 4; ++i)
#pragma unroll
    for (int j = 0; j < 4; ++j) acc[i][j] = 0.f;
  const int xr = t >> 2, xk = (t & 3) * 4;
  const int wk = t >> 4, wc = (t & 15) * 4;
  for (int k0 = 0; k0 < K; k0 += TK) {
    {
      const float* xp = X + (size_t)(m0 + xr) * ldx + (k0 + xk);
      float xv[4];
      if (k0 + xk + 3 < K) {
        float4 v = *(const float4*)xp;
        xv[0] = v.x; xv[1] = v.y; xv[2] = v.z; xv[3] = v.w;
      } else {
#pragma unroll
        for (int e = 0; e < 4; ++e) xv[e] = (k0 + xk + e < K) ? xp[e] : 0.f;
      }
#pragma unroll
      for (int e = 0; e < 4; ++e) Xs[xk + e][xr] = xv[e];
    }
    {
      const int kk = k0 + wk;
      const float* wp = W + (size_t)kk * ldw + (n0 + wc);
      const bool kv = kk < K;
#pragma unroll
      for (int e = 0; e < 4; ++e) {
        int n = n0 + wc + e;
        Ws[wk][wc + e] = (kv && n < N) ? wp[e] : 0.f;
      }
    }
    __syncthreads();
#pragma unroll
    for (int k = 0; k < TK; ++k) {
      float4 av = *(const float4*)&Xs[k][tr * 4];
      float4 bv = *(const float4*)&Ws[k][tc * 4];
      float a4[4] = {av.x, av.y, av.z, av.w};
      float b4[4] = {bv.x, bv.y, bv.z, bv.w};
#pragma unroll
      for (int i = 0; i < 4; ++i)
#pragma unroll
        for (int j = 0; j < 4; ++j)
          acc[i][j] = fmaf(a4[i], b4[j], acc[i][j]);
    }
    __syncthreads();
  }
#pragma unroll
  for (int i = 0; i < 4; ++i) {
    const int mrow = m0 + tr * 4 + i;
    float* op = out + (size_t)mrow * ldo;
#pragma unroll
    for (int j = 0; j < 4; ++j) {
      const int n = n0 + tc * 4 + j;
      if (n < N) {
        float v = acc[i][j] + bias[n];
        if (doSilu) v = v / (1.f + expf(-v));
        op[n] = v;
      } else if (n < padN) {
        op[n] = 0.f;
      }
    }
  }
}

// ---------------- quantum pipeline: 1024 threads, 16 waves, 1 tile/wave ----
#define RS 72                 // LDS row stride (ushorts); 144 B
#define PL (64 * RS)          // ushorts per plane (9216 B)

// C = P * Q, 64x64 complex split-bf16 3-product MFMA. Wave w owns tile
// (mt = w>>2, nt = w&3); per thread: C[row = mt*16+quad*4+rg][col = nt*16+l15].
__device__ __forceinline__ void qmm4(
    const ushort_t* __restrict__ Prm, const ushort_t* __restrict__ Qcm,
    float* ore, float* oim, int mt, int nt, int quad, int l15)
{
  f32x4_t aR = (f32x4_t){0.f, 0.f, 0.f, 0.f};
  f32x4_t aN = (f32x4_t){0.f, 0.f, 0.f, 0.f};
  f32x4_t aI = (f32x4_t){0.f, 0.f, 0.f, 0.f};
#pragma unroll
  for (int kb = 0; kb < 2; ++kb) {
    const int ko = kb * 32 + quad * 8;
    const int ra = (mt * 16 + l15) * RS + ko;
    bf16x8_t arh = *(const bf16x8_t*)&Prm[0 * PL + ra];
    bf16x8_t arl = *(const bf16x8_t*)&Prm[1 * PL + ra];
    bf16x8_t aih = *(const bf16x8_t*)&Prm[2 * PL + ra];
    bf16x8_t ail = *(const bf16x8_t*)&Prm[3 * PL + ra];
    const int rb = (nt * 16 + l15) * RS + ko;
    bf16x8_t brh = *(const bf16x8_t*)&Qcm[0 * PL + rb];
    bf16x8_t brl = *(const bf16x8_t*)&Qcm[1 * PL + rb];
    bf16x8_t bih = *(const bf16x8_t*)&Qcm[2 * PL + rb];
    bf16x8_t bil = *(const bf16x8_t*)&Qcm[3 * PL + rb];
    aR = __builtin_amdgcn_mfma_f32_16x16x32_bf16(arh, brh, aR, 0, 0, 0);
    aR = __builtin_amdgcn_mfma_f32_16x16x32_bf16(arh, brl, aR, 0, 0, 0);
    aR = __builtin_amdgcn_mfma_f32_16x16x32_bf16(arl, brh, aR, 0, 0, 0);
    aN = __builtin_amdgcn_mfma_f32_16x16x32_bf16(aih, bih, aN, 0, 0, 0);
    aN = __builtin_amdgcn_mfma_f32_16x16x32_bf16(aih, bil, aN, 0, 0, 0);
    aN = __builtin_amdgcn_mfma_f32_16x16x32_bf16(ail, bih, aN, 0, 0, 0);
    aI = __builtin_amdgcn_mfma_f32_16x16x32_bf16(arh, bih, aI, 0, 0, 0);
    aI = __builtin_amdgcn_mfma_f32_16x16x32_bf16(arh, bil, aI, 0, 0, 0);
    aI = __builtin_amdgcn_mfma_f32_16x16x32_bf16(arl, bih, aI, 0, 0, 0);
    aI = __builtin_amdgcn_mfma_f32_16x16x32_bf16(aih, brh, aI, 0, 0, 0);
    aI = __builtin_amdgcn_mfma_f32_16x16x32_bf16(aih, brl, aI, 0, 0, 0);
    aI = __builtin_amdgcn_mfma_f32_16x16x32_bf16(ail, brh, aI, 0, 0, 0);
  }
#pragma unroll
  for (int rg = 0; rg < 4; ++rg) {
    ore[rg] = aR[rg] - aN[rg];
    oim[rg] = aI[rg];
  }
}

__device__ __forceinline__ void stage_rm4(
    ushort_t* rm, const float* re, const float* im, int mt, int nt,
    int quad, int l15)
{
  unsigned rh[4], rl[4], ih[4], il[4];
#pragma unroll
  for (int rg = 0; rg < 4; ++rg) {
    tsplit(re[rg], rh[rg], rl[rg]);
    tsplit(im[rg], ih[rg], il[rg]);
  }
#pragma unroll
  for (int rg = 0; rg < 4; ++rg) {
    int idx = (mt * 16 + quad * 4 + rg) * RS + nt * 16 + l15;
    rm[0 * PL + idx] = (ushort_t)rh[rg];
    rm[1 * PL + idx] = (ushort_t)rl[rg];
    rm[2 * PL + idx] = (ushort_t)ih[rg];
    rm[3 * PL + idx] = (ushort_t)il[rg];
  }
}

__device__ __forceinline__ void stage_cm4(
    ushort_t* cm, const float* re, const float* im, int mt, int nt,
    int quad, int l15)
{
  unsigned rh[4], rl[4], ih[4], il[4];
#pragma unroll
  for (int rg = 0; rg < 4; ++rg) {
    tsplit(re[rg], rh[rg], rl[rg]);
    tsplit(im[rg], ih[rg], il[rg]);
  }
  int base = (nt * 16 + l15) * RS + mt * 16 + quad * 4;
  uint2 p;
  p.x = rh[0] | (rh[1] << 16); p.y = rh[2] | (rh[3] << 16);
  *(uint2*)&cm[0 * PL + base] = p;
  p.x = rl[0] | (rl[1] << 16); p.y = rl[2] | (rl[3] << 16);
  *(uint2*)&cm[1 * PL + base] = p;
  p.x = ih[0] | (ih[1] << 16); p.y = ih[2] | (ih[3] << 16);
  *(uint2*)&cm[2 * PL + base] = p;
  p.x = il[0] | (il[1] << 16); p.y = il[2] | (il[3] << 16);
  *(uint2*)&cm[3 * PL + base] = p;
}

__device__ __forceinline__ void stage_both4(
    ushort_t* rm, ushort_t* cm, const float* re, const float* im,
    int mt, int nt, int quad, int l15)
{
  stage_rm4(rm, re, im, mt, nt, quad, l15);
  stage_cm4(cm, re, im, mt, nt, quad, l15);
}

__global__ __launch_bounds__(1024, 4) void quantum_kernel(
    const float* __restrict__ pin,      // fused: part[4][256][4096]; else theta
    const float* __restrict__ b2g,      // [4095] (fused only)
    const float* __restrict__ vp,
    const float* __restrict__ Aobs,
    const float* __restrict__ Bobs,
    const float* __restrict__ Dobs,
    float* __restrict__ out,
    int fused)
{
  __shared__ __align__(16) ushort_t PQ[2][8 * PL];   // 2 x 73728 B
  __shared__ float ps[128];
  __shared__ float scr16[16];
  __shared__ float csb[24], snb[24];
  __shared__ float sAf;
  __shared__ int   sS;

  float*  thetas = (float*)&PQ[1][0];   // 16 KB, dead after WHT
  float2* Als    = (float2*)&PQ[0][0];  // 64 x stride-66 complex

  const int t = threadIdx.x;
  const int b = blockIdx.x;
  const int lane = t & 63;
  const int w = t >> 6;                 // wave 0..15
  const int quad = lane >> 4;
  const int l15 = lane & 15;
  const int mt = w >> 2, nt = w & 3;

  // ---- 1. load theta (fused: 4-way split-K reduce + bias), Frobenius ----
  float ssq;
  {
    float4 v = ((const float4*)(pin + (size_t)b * 4096))[t];
    if (fused) {
#pragma unroll
      for (int k = 1; k < 4; ++k) {
        float4 u =
            ((const float4*)(pin + (size_t)k * 256 * 4096 + (size_t)b * 4096))[t];
        v.x += u.x; v.y += u.y; v.z += u.z; v.w += u.w;
      }
      int n0i = 4 * t;
      v.x += b2g[n0i];
      v.y += b2g[n0i + 1];
      v.z += b2g[n0i + 2];
      if (n0i + 3 < 4095) v.w += b2g[n0i + 3];
    }
    if (t == 1023) v.w = 0.f;
    thetas[4 * t + 0] = v.x; thetas[4 * t + 1] = v.y;
    thetas[4 * t + 2] = v.z; thetas[4 * t + 3] = v.w;
    ssq = v.x * v.x + v.y * v.y + v.z * v.z + v.w * v.w;
  }
#pragma unroll
  for (int mm = 1; mm < 64; mm <<= 1) ssq += __shfl_xor(ssq, mm);
  if (lane == 0) scr16[w] = ssq;
  __syncthreads();
  if (w == 0) {
    float s = (lane < 16) ? scr16[lane] : 0.f;
#pragma unroll
    for (int mm = 1; mm < 64; mm <<= 1) s += __shfl_xor(s, mm);
    if (lane == 0) {
      float frob = fmaxf(8.f * sqrtf(s), 1e-3f);   // ||A||_F exact (Pauli orth.)
      sAf = frob;
      float bound = 0.30f * frob;   // GUE lam_max ~ 0.25 frob + 20% margin
      int sc = (bound > 1.f) ? (int)ceilf(log2f(bound)) : 0;
      sS = sc < 0 ? 0 : (sc > 12 ? 12 : sc);
    }
  } else if (w == 1 && lane < 24) {
    float sn, cs;
    sincosf(vp[lane] * 0.5f, &sn, &cs);
    snb[lane] = sn;
    csb[lane] = cs;
  }
  __syncthreads();
  const int sPow = sS;

  // ---- 2. build A via phase-premultiplied WHT (shfl butterflies) ----
  for (int xx = 0; xx < 4; ++xx) {
    const int x = w + 16 * xx;
    const int z = lane;
    int g1 = 0;
#pragma unroll
    for (int bq = 0; bq < 6; ++bq) {
      int xb = (x >> bq) & 1, zb = (z >> bq) & 1;
      int dig = xb ? (zb ? 2 : 1) : (zb ? 3 : 0);
      g1 |= dig << (2 * bq);
    }
    float tv = (g1 == 0) ? 0.f : thetas[g1 - 1];
    int pc = __popc(x & z) & 3;
    float re, im;
    switch (pc) {
      case 0:  re = tv;  im = 0.f;  break;
      case 1:  re = 0.f; im = -tv;  break;
      case 2:  re = -tv; im = 0.f;  break;
      default: re = 0.f; im = tv;   break;
    }
#pragma unroll
    for (int mk = 1; mk < 64; mk <<= 1) {
      float ore = __shfl_xor(re, mk);
      float oim = __shfl_xor(im, mk);
      if (z & mk) { re = ore - re; im = oim - im; }
      else        { re = re + ore; im = im + oim; }
    }
    Als[z * 66 + (z ^ x)] = make_float2(re, im);
  }
  __syncthreads();

  // ---- 3. B = i * A * 2^-s into per-thread C-ownership registers ----
  const float scl = ldexpf(1.f, -sPow);
  float bre[4], bim[4];
#pragma unroll
  for (int rg = 0; rg < 4; ++rg) {
    int row = mt * 16 + quad * 4 + rg;
    int col = nt * 16 + l15;
    float2 v = Als[row * 66 + col];
    bre[rg] = -v.y * scl;   // i*(ar + i*ai) = -ai + i*ar
    bim[rg] =  v.x * scl;
  }
  __syncthreads();   // Als dead; staging may overwrite

  // ---- 4. Taylor-8 exp(B) via Paterson-Stockmeyer (4 matmuls) ----
  ushort_t* b0 = &PQ[0][0];
  ushort_t* b1 = &PQ[1][0];
  stage_both4(b0, b0 + 4 * PL, bre, bim, mt, nt, quad, l15);
  __syncthreads();
  float b2re[4], b2im[4];
  qmm4(b0, b0 + 4 * PL, b2re, b2im, mt, nt, quad, l15);   // B2 = B*B
  stage_both4(b1, b1 + 4 * PL, b2re, b2im, mt, nt, quad, l15);
  __syncthreads();
  float b3re[4], b3im[4];
  qmm4(b1, b0 + 4 * PL, b3re, b3im, mt, nt, quad, l15);   // B3 = B2*B

  const float c3 = 1.f / 6.f, c4 = 1.f / 24.f, c5 = 1.f / 120.f;
  const float c6 = 1.f / 720.f, c7 = 1.f / 5040.f, c8 = 1.f / 40320.f;
  float s1re[4], s1im[4], p0re[4], p0im[4];
#pragma unroll
  for (int rg = 0; rg < 4; ++rg) {
    float dg = (mt == nt && l15 == quad * 4 + rg) ? 1.f : 0.f;
    s1re[rg] = c4 * dg + c5 * bre[rg] + c6 * b2re[rg] + c7 * b3re[rg];
    s1im[rg] =           c5 * bim[rg] + c6 * b2im[rg] + c7 * b3im[rg];
    p0re[rg] = dg + bre[rg] + 0.5f * b2re[rg] + c3 * b3re[rg];
    p0im[rg] =      bim[rg] + 0.5f * b2im[rg] + c3 * b3im[rg];
  }
  float b4re[4], b4im[4];
  qmm4(b1, b1 + 4 * PL, b4re, b4im, mt, nt, quad, l15);   // B4 = B2*B2
#pragma unroll
  for (int rg = 0; rg < 4; ++rg) {
    s1re[rg] += c8 * b4re[rg];
    s1im[rg] += c8 * b4im[rg];
  }
  __syncthreads();
  stage_rm4(b0, s1re, s1im, mt, nt, quad, l15);
  stage_cm4(b0 + 4 * PL, b4re, b4im, mt, nt, quad, l15);
  __syncthreads();
  float ure[4], uim[4];
  qmm4(b0, b0 + 4 * PL, ure, uim, mt, nt, quad, l15);     // S1*B4
#pragma unroll
  for (int rg = 0; rg < 4; ++rg) {
    ure[rg] += p0re[rg];
    uim[rg] += p0im[rg];
  }

  // ---- 5. s squarings, ping-pong, 1 barrier each ----
  int cur = 1;
  for (int q = 0; q < sPow; ++q) {
    ushort_t* bb = &PQ[cur][0];
    stage_both4(bb, bb + 4 * PL, ure, uim, mt, nt, quad, l15);
    __syncthreads();
    qmm4(bb, bb + 4 * PL, ure, uim, mt, nt, quad, l15);
    cur ^= 1;
  }

  // ---- 6. psi = column 0 of U ----
  if (nt == 0 && l15 == 0) {
#pragma unroll
    for (int rg = 0; rg < 4; ++rg) {
      int row = mt * 16 + quad * 4 + rg;
      ps[2 * row] = ure[rg];
      ps[2 * row + 1] = uim[rg];
    }
  }
  __syncthreads();

  // ---- 7. RY/CNOT circuit via wave shuffles (wave 0) ----
  if (t < 64) {
    float pre = ps[2 * t], pim = ps[2 * t + 1];
#pragma unroll
    for (int d = 0; d < 4; ++d) {
#pragma unroll
      for (int q = 0; q < 6; ++q) {
        float s = snb[d * 6 + q], c = csb[d * 6 + q];
        int bpos = 5 - q;
        int bit = (t >> bpos) & 1;
        float ore = __shfl_xor(pre, 1 << bpos);
        float oim = __shfl_xor(pim, 1 << bpos);
        float sg = bit ? s : -s;
        pre = c * pre + sg * ore;
        pim = c * pim + sg * oim;
      }
#pragma unroll
      for (int q = 0; q < 6; ++q) {
        int bc = 5 - q;
        int bt = 5 - ((q + 1) % 6);
        float ore = __shfl_xor(pre, 1 << bt);
        float oim = __shfl_xor(pim, 1 << bt);
        int ctrl = (t >> bc) & 1;
        pre = ctrl ? ore : pre;
        pim = ctrl ? oim : pim;
      }
    }
    ps[2 * t] = pre; ps[2 * t + 1] = pim;
  }
  __syncthreads();

  // ---- 8. pair terms t_ij = conj(psi_i) psi_j (tril), alias buf0 ----
  float* Rt = (float*)&PQ[0][0];
  float* It = Rt + 2016;
  for (int p = t; p < 2016; p += 1024) {
    int i = (int)((1.f + sqrtf(8.f * (float)p + 1.f)) * 0.5f);
    while (i * (i - 1) / 2 > p) --i;
    while (i * (i + 1) / 2 <= p) ++i;
    int j = p - i * (i - 1) / 2;
    float pri = ps[2 * i], pii = ps[2 * i + 1];
    float prj = ps[2 * j], pij = ps[2 * j + 1];
    Rt[p] = pri * prj + pii * pij;
    It[p] = pri * pij - pii * prj;
  }
  __syncthreads();

  // ---- 9. observables: one obs per wave (waves 0..14) ----
  if (w < 15) {
    float xr = ps[2 * lane], xi = ps[2 * lane + 1];
    float mypsq = xr * xr + xi * xi;
    const float* Ap = Aobs + w * 2016;
    const float* Bp = Bobs + w * 2016;
    float part = 0.f;
    for (int p2 = lane; p2 < 1008; p2 += 64) {
      float2 a = *(const float2*)&Ap[2 * p2];
      float2 bb2 = *(const float2*)&Bp[2 * p2];
      float2 rt = *(const float2*)&Rt[2 * p2];
      float2 it = *(const float2*)&It[2 * p2];
      part += a.x * rt.x - bb2.x * it.x;
      part += a.y * rt.y - bb2.y * it.y;
    }
    if (lane < 63) part += Dobs[w * 64 + lane + 1] * mypsq;
#pragma unroll
    for (int mm = 1; mm < 64; mm <<= 1) part += __shfl_xor(part, mm);
    if (lane == 0) out[b * 15 + w] = 2.f * part;
  }
}

// ---------------- launch ----------------
extern "C" void kernel_launch(void* const* d_in, const int* in_sizes, int n_in,
                              void* d_out, int out_size, void* d_ws, size_t ws_size,
                              hipStream_t stream) {
  const float* x  = (const float*)d_in[0];
  const float* W1 = (const float*)d_in[1];
  const float* b1 = (const float*)d_in[2];
  const float* W2 = (const float*)d_in[3];
  const float* b2 = (const float*)d_in[4];
  const float* vp = (const float*)d_in[5];
  const float* Ao = (const float*)d_in[6];
  const float* Bo = (const float*)d_in[7];
  const float* Do = (const float*)d_in[8];
  float* out = (float*)d_out;

  // Workspace layout (bytes). part16 [0,16MB) aliases prep-phase buffers
  // (xh/xl/w1h/w1l/partg1) which are all dead before gemm2 writes part16.
  const size_t O_XH  = 0;          // 0.5 MB
  const size_t O_XL  = 524288;     // 0.5 MB
  const size_t O_W1H = 1048576;    // 4 MB
  const size_t O_W1L = 5242880;    // 4 MB
  const size_t O_PG1 = 9437184;    // 4 MB (gemm1 split-K=2 partials)
  const size_t O_PT  = 0;          // 16 MB (gemm2 split-K=4 partials)
  const size_t O_W2H = 16777216;   // 16 MB
  const size_t O_W2L = 33554432;   // 16 MB
  const size_t O_HH  = 50331648;   // 1 MB
  const size_t O_HL  = 51380224;   // 1 MB
  const size_t NEED  = 52428800;   // 50 MB

  if (ws_size >= NEED) {
    char* ws = (char*)d_ws;
    ushort_t* xh  = (ushort_t*)(ws + O_XH);
    ushort_t* xl  = (ushort_t*)(ws + O_XL);
    ushort_t* w1h = (ushort_t*)(ws + O_W1H);
    ushort_t* w1l = (ushort_t*)(ws + O_W1L);
    float* partg1 = (float*)(ws + O_PG1);
    float* part16 = (float*)(ws + O_PT);
    ushort_t* w2h = (ushort_t*)(ws + O_W2H);
    ushort_t* w2l = (ushort_t*)(ws + O_W2L);
    ushort_t* hh  = (ushort_t*)(ws + O_HH);
    ushort_t* hl  = (ushort_t*)(ws + O_HL);

    // one prep dispatch: split x + transpose/split W1 + W2
    prep_kernel<<<10496, 256, 0, stream>>>(x, W1, W2, xh, xl, w1h, w1l, w2h, w2l);
    // GEMM1: [256x1024] x [2048x1024]^T, split-K=2
    gemm_fused_kernel<<<dim3(32, 4, 2), 256, 0, stream>>>(
        xh, xl, w1h, w1l, partg1, 1024, 512, 2048);
    reduce1_kernel<<<2048, 256, 0, stream>>>(partg1, b1, hh, hl);
    // GEMM2: [256x2048] x [4096x2048]^T, 128m-tile, split-K=4
    gemm2k_kernel<<<dim3(64, 2, 4), 256, 0, stream>>>(hh, hl, w2h, w2l, part16);
    // quantum (fused 4-way reduce + bias)
    quantum_kernel<<<256, 1024, 0, stream>>>(part16, b2, vp, Ao, Bo, Do, out, 1);
  } else {
    float* h     = (float*)d_ws;
    float* theta = h + 256 * 2048;
    gemm_tiled<<<dim3(32, 4), 256, 0, stream>>>(
        x, W1, b1, h, 256, 2047, 1024, 1024, 2047, 2048, 1, 2048);
    gemm_tiled<<<dim3(64, 4), 256, 0, stream>>>(
        h, W2, b2, theta, 256, 4095, 2047, 2048, 4095, 4096, 0, 4096);
    quantum_kernel<<<256, 1024, 0, stream>>>(theta, b2, vp, Ao, Bo, Do, out, 0);
  }
}

// Round 9
// 174.680 us; speedup vs baseline: 1.0377x; 1.0377x over previous
//
#include <hip/hip_runtime.h>
#include <math.h>

typedef unsigned short ushort_t;
typedef __attribute__((ext_vector_type(8))) short bf16x8_t;
typedef __attribute__((ext_vector_type(4))) float f32x4_t;

// ---------------- split helpers ----------------
// Truncation split: hi = trunc16(v), lo = trunc16(v - hi); |err| <= 2^-16 |v|.
__device__ __forceinline__ void tsplit(float v, unsigned& h, unsigned& l) {
  unsigned u = __float_as_uint(v);
  h = u >> 16;
  float lo = v - __uint_as_float(u & 0xffff0000u);
  l = __float_as_uint(lo) >> 16;
}

// ---------------- W transpose/split tile (proven round 7/8) ----------------
__device__ __forceinline__ void transpose_tile(
    const float* __restrict__ W, ushort_t* __restrict__ Wh,
    ushort_t* __restrict__ Wl, int K, int N, int Kpad, int n0, int k0, int t) {
  __shared__ float sh[32][33];   // sh[n][k]
  const int tx = t & 31, ty = t >> 5;
#pragma unroll
  for (int i = 0; i < 4; ++i) {
    int k = k0 + i * 8 + ty;
    float v = (k < K && (n0 + tx) < N) ? W[(size_t)k * N + n0 + tx] : 0.f;
    sh[tx][i * 8 + ty] = v;
  }
  __syncthreads();
  const int nn = t >> 3;        // 0..31
  const int kq = t & 7;         // 0..7 -> 4 consecutive k
  unsigned h[4], l[4];
#pragma unroll
  for (int e = 0; e < 4; ++e) tsplit(sh[nn][kq * 4 + e], h[e], l[e]);
  size_t o = (size_t)(n0 + nn) * Kpad + k0 + kq * 4;
  uint2 ph, pl;
  ph.x = h[0] | (h[1] << 16); ph.y = h[2] | (h[3] << 16);
  pl.x = l[0] | (l[1] << 16); pl.y = l[2] | (l[3] << 16);
  *(uint2*)&Wh[o] = ph;
  *(uint2*)&Wl[o] = pl;
}

// ---------------- prep2: split x + transpose/split W1 ----------------
__global__ __launch_bounds__(256) void prep2_kernel(
    const float* __restrict__ x, const float* __restrict__ W1,
    ushort_t* __restrict__ xh, ushort_t* __restrict__ xl,
    ushort_t* __restrict__ w1h, ushort_t* __restrict__ w1l) {
  const int bid = blockIdx.x;
  const int t = threadIdx.x;
  if (bid < 256) {
    int i4 = bid * 256 + t;
    float4 v = ((const float4*)x)[i4];
    unsigned h0, l0, h1, l1, h2, l2, h3, l3;
    tsplit(v.x, h0, l0); tsplit(v.y, h1, l1);
    tsplit(v.z, h2, l2); tsplit(v.w, h3, l3);
    uint2 ph, pl;
    ph.x = h0 | (h1 << 16); ph.y = h2 | (h3 << 16);
    pl.x = l0 | (l1 << 16); pl.y = l2 | (l3 << 16);
    ((uint2*)xh)[i4] = ph;
    ((uint2*)xl)[i4] = pl;
  } else {
    int tau = bid - 256;                 // W1: 64 n-tiles x 32 k-tiles
    transpose_tile(W1, w1h, w1l, 1024, 2047, 1024,
                   (tau & 63) * 32, (tau >> 6) * 32, t);
  }
}

#define LSTR 40

// ---------------- gemm1 (fused epilogue) + W2-transpose, one dispatch ------
// Blocks 0..255: h = silu(x @ W1 + b1) -> hh/hl, tile 32m x 64n, full K.
// Blocks 256..8447: W2 [2047][4095] -> w2h/w2l [4096][2048] (k-major).
// W2T output is consumed only by the NEXT dispatch (gemm2) -> ordering safe.
__global__ __launch_bounds__(256) void gemm1_w2t_kernel(
    const ushort_t* __restrict__ xh, const ushort_t* __restrict__ xl,
    const ushort_t* __restrict__ w1h, const ushort_t* __restrict__ w1l,
    const float* __restrict__ b1,
    ushort_t* __restrict__ hh, ushort_t* __restrict__ hl,
    const float* __restrict__ W2,
    ushort_t* __restrict__ w2h, ushort_t* __restrict__ w2l) {
  const int bid = blockIdx.x;
  const int t = threadIdx.x;
  if (bid >= 256) {
    int tau = bid - 256;                 // W2: 128 n-tiles x 64 k-tiles
    transpose_tile(W2, w2h, w2l, 2047, 4095, 2048,
                   (tau & 127) * 32, (tau >> 7) * 32, t);
    return;
  }
  __shared__ ushort_t As[2][32 * LSTR];
  __shared__ ushort_t Bs[2][64 * LSTR];
  const int lane = t & 63;
  const int wv = t >> 6;
  const int l15 = lane & 15;
  const int quad = lane >> 4;
  const int m0 = (bid >> 5) * 32;
  const int n0 = (bid & 31) * 64;

  f32x4_t acc[2];
  acc[0] = (f32x4_t){0.f, 0.f, 0.f, 0.f};
  acc[1] = (f32x4_t){0.f, 0.f, 0.f, 0.f};

  for (int k0 = 0; k0 < 1024; k0 += 32) {
    if (wv < 2) {
      // A: 32 rows x 32 k, one plane per wave
      const ushort_t* src = wv ? xl : xh;
      ushort_t* dst = As[wv];
#pragma unroll
      for (int q = 0; q < 2; ++q) {
        int r = q * 16 + (lane >> 2);
        int c = (lane & 3) * 8;
        *(int4*)&dst[r * LSTR + c] =
            *(const int4*)(src + (size_t)(m0 + r) * 1024 + k0 + c);
      }
    } else {
      // B: 64 rows x 32 k, one plane per wave
      const ushort_t* src = (wv == 3) ? w1l : w1h;
      ushort_t* dst = Bs[wv - 2];
#pragma unroll
      for (int q = 0; q < 4; ++q) {
        int r = q * 16 + (lane >> 2);
        int c = (lane & 3) * 8;
        *(int4*)&dst[r * LSTR + c] =
            *(const int4*)(src + (size_t)(n0 + r) * 1024 + k0 + c);
      }
    }
    __syncthreads();
    bf16x8_t bfh = *(const bf16x8_t*)&Bs[0][(wv * 16 + l15) * LSTR + quad * 8];
    bf16x8_t bfl = *(const bf16x8_t*)&Bs[1][(wv * 16 + l15) * LSTR + quad * 8];
#pragma unroll
    for (int i = 0; i < 2; ++i) {
      int mr = i * 16 + l15;
      bf16x8_t afh = *(const bf16x8_t*)&As[0][mr * LSTR + quad * 8];
      bf16x8_t afl = *(const bf16x8_t*)&As[1][mr * LSTR + quad * 8];
      acc[i] = __builtin_amdgcn_mfma_f32_16x16x32_bf16(afh, bfh, acc[i], 0, 0, 0);
      acc[i] = __builtin_amdgcn_mfma_f32_16x16x32_bf16(afh, bfl, acc[i], 0, 0, 0);
      acc[i] = __builtin_amdgcn_mfma_f32_16x16x32_bf16(afl, bfh, acc[i], 0, 0, 0);
    }
    __syncthreads();
  }
  // epilogue: bias + silu + split -> hh/hl (col 2047 = 0 pad)
#pragma unroll
  for (int i = 0; i < 2; ++i) {
    int col = n0 + wv * 16 + l15;
#pragma unroll
    for (int rg = 0; rg < 4; ++rg) {
      int row = m0 + i * 16 + quad * 4 + rg;
      float v = acc[i][rg];
      if (col < 2047) {
        v += b1[col];
        v = v / (1.f + expf(-v));
      } else {
        v = 0.f;
      }
      unsigned h, l;
      tsplit(v, h, l);
      size_t o = (size_t)row * 2048 + col;
      hh[o] = (ushort_t)h;
      hl[o] = (ushort_t)l;
    }
  }
}

// ---------------- GEMM2: 128m x 64n tile, split-K=4 (round-8) ----------------
__global__ __launch_bounds__(256) void gemm2k_kernel(
    const ushort_t* __restrict__ Ah, const ushort_t* __restrict__ Al,
    const ushort_t* __restrict__ Bh, const ushort_t* __restrict__ Bl,
    float* __restrict__ part) {
  __shared__ ushort_t Ab[2][128 * LSTR];
  __shared__ ushort_t Bb[2][64 * LSTR];
  const int t = threadIdx.x;
  const int lane = t & 63;
  const int wv = t >> 6;
  const int l15 = lane & 15;
  const int quad = lane >> 4;
  const int wm = wv >> 1, wn = wv & 1;
  const int m0 = blockIdx.y * 128;
  const int n0 = blockIdx.x * 64;
  const int ks = blockIdx.z;

  f32x4_t acc[4][2];
#pragma unroll
  for (int i = 0; i < 4; ++i)
#pragma unroll
    for (int j = 0; j < 2; ++j) acc[i][j] = (f32x4_t){0.f, 0.f, 0.f, 0.f};

  for (int kt = 0; kt < 16; ++kt) {
    const int k0 = ks * 512 + kt * 32;
    if (wv < 2) {
      const ushort_t* src = wv ? Al : Ah;
      ushort_t* dst = Ab[wv];
#pragma unroll
      for (int q = 0; q < 8; ++q) {
        int r = q * 16 + (lane >> 2);
        int c = (lane & 3) * 8;
        *(int4*)&dst[r * LSTR + c] =
            *(const int4*)(src + (size_t)(m0 + r) * 2048 + k0 + c);
      }
    } else {
      const ushort_t* src = (wv == 3) ? Bl : Bh;
      ushort_t* dst = Bb[wv - 2];
#pragma unroll
      for (int q = 0; q < 4; ++q) {
        int r = q * 16 + (lane >> 2);
        int c = (lane & 3) * 8;
        *(int4*)&dst[r * LSTR + c] =
            *(const int4*)(src + (size_t)(n0 + r) * 2048 + k0 + c);
      }
    }
    __syncthreads();
    bf16x8_t bfh[2], bfl[2];
#pragma unroll
    for (int j = 0; j < 2; ++j) {
      int nr = wn * 32 + j * 16 + l15;
      bfh[j] = *(const bf16x8_t*)&Bb[0][nr * LSTR + quad * 8];
      bfl[j] = *(const bf16x8_t*)&Bb[1][nr * LSTR + quad * 8];
    }
#pragma unroll
    for (int i = 0; i < 4; ++i) {
      int mr = wm * 64 + i * 16 + l15;
      bf16x8_t afh = *(const bf16x8_t*)&Ab[0][mr * LSTR + quad * 8];
      bf16x8_t afl = *(const bf16x8_t*)&Ab[1][mr * LSTR + quad * 8];
#pragma unroll
      for (int j = 0; j < 2; ++j) {
        acc[i][j] = __builtin_amdgcn_mfma_f32_16x16x32_bf16(
            afh, bfh[j], acc[i][j], 0, 0, 0);
        acc[i][j] = __builtin_amdgcn_mfma_f32_16x16x32_bf16(
            afh, bfl[j], acc[i][j], 0, 0, 0);
        acc[i][j] = __builtin_amdgcn_mfma_f32_16x16x32_bf16(
            afl, bfh[j], acc[i][j], 0, 0, 0);
      }
    }
    __syncthreads();
  }
  float* pbase = part + (size_t)ks * 256 * 4096;
#pragma unroll
  for (int i = 0; i < 4; ++i)
#pragma unroll
    for (int j = 0; j < 2; ++j) {
      int row0 = m0 + wm * 64 + i * 16 + quad * 4;
      int col = n0 + wn * 32 + j * 16 + l15;
#pragma unroll
      for (int rg = 0; rg < 4; ++rg)
        pbase[(size_t)(row0 + rg) * 4096 + col] = acc[i][j][rg];
    }
}

// ---------------- fallback fp32 GEMM (round-1, known-good) ----------------
#define TM 64
#define TN 64
#define TK 16
__global__ __launch_bounds__(256) void gemm_tiled(
    const float* __restrict__ X, const float* __restrict__ W,
    const float* __restrict__ bias, float* __restrict__ out,
    int M, int N, int K, int ldx, int ldw, int ldo, int doSilu, int padN)
{
  __shared__ float Xs[TK][TM + 4];
  __shared__ float Ws[TK][TN + 4];
  const int t = threadIdx.x;
  const int n0 = blockIdx.x * TN;
  const int m0 = blockIdx.y * TM;
  const int tr = t >> 4, tc = t & 15;
  float acc[4][4];
#pragma unroll
  for (int i = 0; i < 4; ++i)
#pragma unroll
    for (int j = 0; j < 4; ++j) acc[i][j] = 0.f;
  const int xr = t >> 2, xk = (t & 3) * 4;
  const int wk = t >> 4, wc = (t & 15) * 4;
  for (int k0 = 0; k0 < K; k0 += TK) {
    {
      const float* xp = X + (size_t)(m0 + xr) * ldx + (k0 + xk);
      float xv[4];
      if (k0 + xk + 3 < K) {
        float4 v = *(const float4*)xp;
        xv[0] = v.x; xv[1] = v.y; xv[2] = v.z; xv[3] = v.w;
      } else {
#pragma unroll
        for (int e = 0; e < 4; ++e) xv[e] = (k0 + xk + e < K) ? xp[e] : 0.f;
      }
#pragma unroll
      for (int e = 0; e < 4; ++e) Xs[xk + e][xr] = xv[e];
    }
    {
      const int kk = k0 + wk;
      const float* wp = W + (size_t)kk * ldw + (n0 + wc);
      const bool kv = kk < K;
#pragma unroll
      for (int e = 0; e < 4; ++e) {
        int n = n0 + wc + e;
        Ws[wk][wc + e] = (kv && n < N) ? wp[e] : 0.f;
      }
    }
    __syncthreads();
#pragma unroll
    for (int k = 0; k < TK; ++k) {
      float4 av = *(const float4*)&Xs[k][tr * 4];
      float4 bv = *(const float4*)&Ws[k][tc * 4];
      float a4[4] = {av.x, av.y, av.z, av.w};
      float b4[4] = {bv.x, bv.y, bv.z, bv.w};
#pragma unroll
      for (int i = 0; i < 4; ++i)
#pragma unroll
        for (int j = 0; j < 4; ++j)
          acc[i][j] = fmaf(a4[i], b4[j], acc[i][j]);
    }
    __syncthreads();
  }
#pragma unroll
  for (int i = 0; i < 4; ++i) {
    const int mrow = m0 + tr * 4 + i;
    float* op = out + (size_t)mrow * ldo;
#pragma unroll
    for (int j = 0; j < 4; ++j) {
      const int n = n0 + tc * 4 + j;
      if (n < N) {
        float v = acc[i][j] + bias[n];
        if (doSilu) v = v / (1.f + expf(-v));
        op[n] = v;
      } else if (n < padN) {
        op[n] = 0.f;
      }
    }
  }
}

// ---------------- quantum pipeline: 1024 threads, 16 waves, 1 tile/wave ----
#define RS 72
#define PL (64 * RS)

__device__ __forceinline__ void qmm4(
    const ushort_t* __restrict__ Prm, const ushort_t* __restrict__ Qcm,
    float* ore, float* oim, int mt, int nt, int quad, int l15)
{
  f32x4_t aR = (f32x4_t){0.f, 0.f, 0.f, 0.f};
  f32x4_t aN = (f32x4_t){0.f, 0.f, 0.f, 0.f};
  f32x4_t aI = (f32x4_t){0.f, 0.f, 0.f, 0.f};
#pragma unroll
  for (int kb = 0; kb < 2; ++kb) {
    const int ko = kb * 32 + quad * 8;
    const int ra = (mt * 16 + l15) * RS + ko;
    bf16x8_t arh = *(const bf16x8_t*)&Prm[0 * PL + ra];
    bf16x8_t arl = *(const bf16x8_t*)&Prm[1 * PL + ra];
    bf16x8_t aih = *(const bf16x8_t*)&Prm[2 * PL + ra];
    bf16x8_t ail = *(const bf16x8_t*)&Prm[3 * PL + ra];
    const int rb = (nt * 16 + l15) * RS + ko;
    bf16x8_t brh = *(const bf16x8_t*)&Qcm[0 * PL + rb];
    bf16x8_t brl = *(const bf16x8_t*)&Qcm[1 * PL + rb];
    bf16x8_t bih = *(const bf16x8_t*)&Qcm[2 * PL + rb];
    bf16x8_t bil = *(const bf16x8_t*)&Qcm[3 * PL + rb];
    aR = __builtin_amdgcn_mfma_f32_16x16x32_bf16(arh, brh, aR, 0, 0, 0);
    aR = __builtin_amdgcn_mfma_f32_16x16x32_bf16(arh, brl, aR, 0, 0, 0);
    aR = __builtin_amdgcn_mfma_f32_16x16x32_bf16(arl, brh, aR, 0, 0, 0);
    aN = __builtin_amdgcn_mfma_f32_16x16x32_bf16(aih, bih, aN, 0, 0, 0);
    aN = __builtin_amdgcn_mfma_f32_16x16x32_bf16(aih, bil, aN, 0, 0, 0);
    aN = __builtin_amdgcn_mfma_f32_16x16x32_bf16(ail, bih, aN, 0, 0, 0);
    aI = __builtin_amdgcn_mfma_f32_16x16x32_bf16(arh, bih, aI, 0, 0, 0);
    aI = __builtin_amdgcn_mfma_f32_16x16x32_bf16(arh, bil, aI, 0, 0, 0);
    aI = __builtin_amdgcn_mfma_f32_16x16x32_bf16(arl, bih, aI, 0, 0, 0);
    aI = __builtin_amdgcn_mfma_f32_16x16x32_bf16(aih, brh, aI, 0, 0, 0);
    aI = __builtin_amdgcn_mfma_f32_16x16x32_bf16(aih, brl, aI, 0, 0, 0);
    aI = __builtin_amdgcn_mfma_f32_16x16x32_bf16(ail, brh, aI, 0, 0, 0);
  }
#pragma unroll
  for (int rg = 0; rg < 4; ++rg) {
    ore[rg] = aR[rg] - aN[rg];
    oim[rg] = aI[rg];
  }
}

__device__ __forceinline__ void stage_rm4(
    ushort_t* rm, const float* re, const float* im, int mt, int nt,
    int quad, int l15)
{
  unsigned rh[4], rl[4], ih[4], il[4];
#pragma unroll
  for (int rg = 0; rg < 4; ++rg) {
    tsplit(re[rg], rh[rg], rl[rg]);
    tsplit(im[rg], ih[rg], il[rg]);
  }
#pragma unroll
  for (int rg = 0; rg < 4; ++rg) {
    int idx = (mt * 16 + quad * 4 + rg) * RS + nt * 16 + l15;
    rm[0 * PL + idx] = (ushort_t)rh[rg];
    rm[1 * PL + idx] = (ushort_t)rl[rg];
    rm[2 * PL + idx] = (ushort_t)ih[rg];
    rm[3 * PL + idx] = (ushort_t)il[rg];
  }
}

__device__ __forceinline__ void stage_cm4(
    ushort_t* cm, const float* re, const float* im, int mt, int nt,
    int quad, int l15)
{
  unsigned rh[4], rl[4], ih[4], il[4];
#pragma unroll
  for (int rg = 0; rg < 4; ++rg) {
    tsplit(re[rg], rh[rg], rl[rg]);
    tsplit(im[rg], ih[rg], il[rg]);
  }
  int base = (nt * 16 + l15) * RS + mt * 16 + quad * 4;
  uint2 p;
  p.x = rh[0] | (rh[1] << 16); p.y = rh[2] | (rh[3] << 16);
  *(uint2*)&cm[0 * PL + base] = p;
  p.x = rl[0] | (rl[1] << 16); p.y = rl[2] | (rl[3] << 16);
  *(uint2*)&cm[1 * PL + base] = p;
  p.x = ih[0] | (ih[1] << 16); p.y = ih[2] | (ih[3] << 16);
  *(uint2*)&cm[2 * PL + base] = p;
  p.x = il[0] | (il[1] << 16); p.y = il[2] | (il[3] << 16);
  *(uint2*)&cm[3 * PL + base] = p;
}

__device__ __forceinline__ void stage_both4(
    ushort_t* rm, ushort_t* cm, const float* re, const float* im,
    int mt, int nt, int quad, int l15)
{
  stage_rm4(rm, re, im, mt, nt, quad, l15);
  stage_cm4(cm, re, im, mt, nt, quad, l15);
}

__global__ __launch_bounds__(1024, 4) void quantum_kernel(
    const float* __restrict__ pin,      // fused: part[4][256][4096]; else theta
    const float* __restrict__ b2g,      // [4095] (fused only)
    const float* __restrict__ vp,
    const float* __restrict__ Aobs,
    const float* __restrict__ Bobs,
    const float* __restrict__ Dobs,
    float* __restrict__ out,
    int fused)
{
  __shared__ __align__(16) ushort_t PQ[2][8 * PL];
  __shared__ float ps[128];
  __shared__ float scr16[16];
  __shared__ float csb[24], snb[24];
  __shared__ float sAf;
  __shared__ int   sS;

  float*  thetas = (float*)&PQ[1][0];
  float2* Als    = (float2*)&PQ[0][0];

  const int t = threadIdx.x;
  const int b = blockIdx.x;
  const int lane = t & 63;
  const int w = t >> 6;
  const int quad = lane >> 4;
  const int l15 = lane & 15;
  const int mt = w >> 2, nt = w & 3;

  // ---- 1. load theta (fused: 4-way split-K reduce + bias), Frobenius ----
  float ssq;
  {
    float4 v = ((const float4*)(pin + (size_t)b * 4096))[t];
    if (fused) {
#pragma unroll
      for (int k = 1; k < 4; ++k) {
        float4 u =
            ((const float4*)(pin + (size_t)k * 256 * 4096 + (size_t)b * 4096))[t];
        v.x += u.x; v.y += u.y; v.z += u.z; v.w += u.w;
      }
      int n0i = 4 * t;
      v.x += b2g[n0i];
      v.y += b2g[n0i + 1];
      v.z += b2g[n0i + 2];
      if (n0i + 3 < 4095) v.w += b2g[n0i + 3];
    }
    if (t == 1023) v.w = 0.f;
    thetas[4 * t + 0] = v.x; thetas[4 * t + 1] = v.y;
    thetas[4 * t + 2] = v.z; thetas[4 * t + 3] = v.w;
    ssq = v.x * v.x + v.y * v.y + v.z * v.z + v.w * v.w;
  }
#pragma unroll
  for (int mm = 1; mm < 64; mm <<= 1) ssq += __shfl_xor(ssq, mm);
  if (lane == 0) scr16[w] = ssq;
  __syncthreads();
  if (w == 0) {
    float s = (lane < 16) ? scr16[lane] : 0.f;
#pragma unroll
    for (int mm = 1; mm < 64; mm <<= 1) s += __shfl_xor(s, mm);
    if (lane == 0) {
      float frob = fmaxf(8.f * sqrtf(s), 1e-3f);
      sAf = frob;
      float bound = 0.30f * frob;   // GUE lam_max ~ 0.25 frob + 20% margin
      int sc = (bound > 1.f) ? (int)ceilf(log2f(bound)) : 0;
      sS = sc < 0 ? 0 : (sc > 12 ? 12 : sc);
    }
  } else if (w == 1 && lane < 24) {
    float sn, cs;
    sincosf(vp[lane] * 0.5f, &sn, &cs);
    snb[lane] = sn;
    csb[lane] = cs;
  }
  __syncthreads();
  const int sPow = sS;

  // ---- 2. build A via phase-premultiplied WHT (shfl butterflies) ----
  for (int xx = 0; xx < 4; ++xx) {
    const int x = w + 16 * xx;
    const int z = lane;
    int g1 = 0;
#pragma unroll
    for (int bq = 0; bq < 6; ++bq) {
      int xb = (x >> bq) & 1, zb = (z >> bq) & 1;
      int dig = xb ? (zb ? 2 : 1) : (zb ? 3 : 0);
      g1 |= dig << (2 * bq);
    }
    float tv = (g1 == 0) ? 0.f : thetas[g1 - 1];
    int pc = __popc(x & z) & 3;
    float re, im;
    switch (pc) {
      case 0:  re = tv;  im = 0.f;  break;
      case 1:  re = 0.f; im = -tv;  break;
      case 2:  re = -tv; im = 0.f;  break;
      default: re = 0.f; im = tv;   break;
    }
#pragma unroll
    for (int mk = 1; mk < 64; mk <<= 1) {
      float ore = __shfl_xor(re, mk);
      float oim = __shfl_xor(im, mk);
      if (z & mk) { re = ore - re; im = oim - im; }
      else        { re = re + ore; im = im + oim; }
    }
    Als[z * 66 + (z ^ x)] = make_float2(re, im);
  }
  __syncthreads();

  // ---- 3. B = i * A * 2^-s into per-thread C-ownership registers ----
  const float scl = ldexpf(1.f, -sPow);
  float bre[4], bim[4];
#pragma unroll
  for (int rg = 0; rg < 4; ++rg) {
    int row = mt * 16 + quad * 4 + rg;
    int col = nt * 16 + l15;
    float2 v = Als[row * 66 + col];
    bre[rg] = -v.y * scl;
    bim[rg] =  v.x * scl;
  }
  __syncthreads();

  // ---- 4. Taylor-8 exp(B) via Paterson-Stockmeyer (4 matmuls) ----
  ushort_t* b0 = &PQ[0][0];
  ushort_t* b1 = &PQ[1][0];
  stage_both4(b0, b0 + 4 * PL, bre, bim, mt, nt, quad, l15);
  __syncthreads();
  float b2re[4], b2im[4];
  qmm4(b0, b0 + 4 * PL, b2re, b2im, mt, nt, quad, l15);   // B2 = B*B
  stage_both4(b1, b1 + 4 * PL, b2re, b2im, mt, nt, quad, l15);
  __syncthreads();
  float b3re[4], b3im[4];
  qmm4(b1, b0 + 4 * PL, b3re, b3im, mt, nt, quad, l15);   // B3 = B2*B

  const float c3 = 1.f / 6.f, c4 = 1.f / 24.f, c5 = 1.f / 120.f;
  const float c6 = 1.f / 720.f, c7 = 1.f / 5040.f, c8 = 1.f / 40320.f;
  float s1re[4], s1im[4], p0re[4], p0im[4];
#pragma unroll
  for (int rg = 0; rg < 4; ++rg) {
    float dg = (mt == nt && l15 == quad * 4 + rg) ? 1.f : 0.f;
    s1re[rg] = c4 * dg + c5 * bre[rg] + c6 * b2re[rg] + c7 * b3re[rg];
    s1im[rg] =           c5 * bim[rg] + c6 * b2im[rg] + c7 * b3im[rg];
    p0re[rg] = dg + bre[rg] + 0.5f * b2re[rg] + c3 * b3re[rg];
    p0im[rg] =      bim[rg] + 0.5f * b2im[rg] + c3 * b3im[rg];
  }
  float b4re[4], b4im[4];
  qmm4(b1, b1 + 4 * PL, b4re, b4im, mt, nt, quad, l15);   // B4 = B2*B2
#pragma unroll
  for (int rg = 0; rg < 4; ++rg) {
    s1re[rg] += c8 * b4re[rg];
    s1im[rg] += c8 * b4im[rg];
  }
  __syncthreads();
  stage_rm4(b0, s1re, s1im, mt, nt, quad, l15);
  stage_cm4(b0 + 4 * PL, b4re, b4im, mt, nt, quad, l15);
  __syncthreads();
  float ure[4], uim[4];
  qmm4(b0, b0 + 4 * PL, ure, uim, mt, nt, quad, l15);     // S1*B4
#pragma unroll
  for (int rg = 0; rg < 4; ++rg) {
    ure[rg] += p0re[rg];
    uim[rg] += p0im[rg];
  }

  // ---- 5. s squarings, ping-pong, 1 barrier each ----
  int cur = 1;
  for (int q = 0; q < sPow; ++q) {
    ushort_t* bb = &PQ[cur][0];
    stage_both4(bb, bb + 4 * PL, ure, uim, mt, nt, quad, l15);
    __syncthreads();
    qmm4(bb, bb + 4 * PL, ure, uim, mt, nt, quad, l15);
    cur ^= 1;
  }

  // ---- 6. psi = column 0 of U ----
  if (nt == 0 && l15 == 0) {
#pragma unroll
    for (int rg = 0; rg < 4; ++rg) {
      int row = mt * 16 + quad * 4 + rg;
      ps[2 * row] = ure[rg];
      ps[2 * row + 1] = uim[rg];
    }
  }
  __syncthreads();

  // ---- 7. RY/CNOT circuit via wave shuffles (wave 0) ----
  if (t < 64) {
    float pre = ps[2 * t], pim = ps[2 * t + 1];
#pragma unroll
    for (int d = 0; d < 4; ++d) {
#pragma unroll
      for (int q = 0; q < 6; ++q) {
        float s = snb[d * 6 + q], c = csb[d * 6 + q];
        int bpos = 5 - q;
        int bit = (t >> bpos) & 1;
        float ore = __shfl_xor(pre, 1 << bpos);
        float oim = __shfl_xor(pim, 1 << bpos);
        float sg = bit ? s : -s;
        pre = c * pre + sg * ore;
        pim = c * pim + sg * oim;
      }
#pragma unroll
      for (int q = 0; q < 6; ++q) {
        int bc = 5 - q;
        int bt = 5 - ((q + 1) % 6);
        float ore = __shfl_xor(pre, 1 << bt);
        float oim = __shfl_xor(pim, 1 << bt);
        int ctrl = (t >> bc) & 1;
        pre = ctrl ? ore : pre;
        pim = ctrl ? oim : pim;
      }
    }
    ps[2 * t] = pre; ps[2 * t + 1] = pim;
  }
  __syncthreads();

  // ---- 8. pair terms t_ij = conj(psi_i) psi_j (tril), alias buf0 ----
  float* Rt = (float*)&PQ[0][0];
  float* It = Rt + 2016;
  for (int p = t; p < 2016; p += 1024) {
    int i = (int)((1.f + sqrtf(8.f * (float)p + 1.f)) * 0.5f);
    while (i * (i - 1) / 2 > p) --i;
    while (i * (i + 1) / 2 <= p) ++i;
    int j = p - i * (i - 1) / 2;
    float pri = ps[2 * i], pii = ps[2 * i + 1];
    float prj = ps[2 * j], pij = ps[2 * j + 1];
    Rt[p] = pri * prj + pii * pij;
    It[p] = pri * pij - pii * prj;
  }
  __syncthreads();

  // ---- 9. observables: one obs per wave (waves 0..14) ----
  if (w < 15) {
    float xr = ps[2 * lane], xi = ps[2 * lane + 1];
    float mypsq = xr * xr + xi * xi;
    const float* Ap = Aobs + w * 2016;
    const float* Bp = Bobs + w * 2016;
    float part = 0.f;
    for (int p2 = lane; p2 < 1008; p2 += 64) {
      float2 a = *(const float2*)&Ap[2 * p2];
      float2 bb2 = *(const float2*)&Bp[2 * p2];
      float2 rt = *(const float2*)&Rt[2 * p2];
      float2 it = *(const float2*)&It[2 * p2];
      part += a.x * rt.x - bb2.x * it.x;
      part += a.y * rt.y - bb2.y * it.y;
    }
    if (lane < 63) part += Dobs[w * 64 + lane + 1] * mypsq;
#pragma unroll
    for (int mm = 1; mm < 64; mm <<= 1) part += __shfl_xor(part, mm);
    if (lane == 0) out[b * 15 + w] = 2.f * part;
  }
}

// ---------------- launch ----------------
extern "C" void kernel_launch(void* const* d_in, const int* in_sizes, int n_in,
                              void* d_out, int out_size, void* d_ws, size_t ws_size,
                              hipStream_t stream) {
  const float* x  = (const float*)d_in[0];
  const float* W1 = (const float*)d_in[1];
  const float* b1 = (const float*)d_in[2];
  const float* W2 = (const float*)d_in[3];
  const float* b2 = (const float*)d_in[4];
  const float* vp = (const float*)d_in[5];
  const float* Ao = (const float*)d_in[6];
  const float* Bo = (const float*)d_in[7];
  const float* Do = (const float*)d_in[8];
  float* out = (float*)d_out;

  // Workspace (bytes). part16 [0,16MB) aliases xh/xl/w1h/w1l, which are dead
  // after the gemm1_w2t dispatch completes (before gemm2 writes part16).
  const size_t O_XH  = 0;          // 0.5 MB
  const size_t O_XL  = 524288;     // 0.5 MB
  const size_t O_W1H = 1048576;    // 4 MB
  const size_t O_W1L = 5242880;    // 4 MB
  const size_t O_PT  = 0;          // 16 MB (gemm2 split-K=4 partials)
  const size_t O_W2H = 16777216;   // 16 MB
  const size_t O_W2L = 33554432;   // 16 MB
  const size_t O_HH  = 50331648;   // 1 MB
  const size_t O_HL  = 51380224;   // 1 MB
  const size_t NEED  = 52428800;   // 50 MB

  if (ws_size >= NEED) {
    char* ws = (char*)d_ws;
    ushort_t* xh  = (ushort_t*)(ws + O_XH);
    ushort_t* xl  = (ushort_t*)(ws + O_XL);
    ushort_t* w1h = (ushort_t*)(ws + O_W1H);
    ushort_t* w1l = (ushort_t*)(ws + O_W1L);
    float* part16 = (float*)(ws + O_PT);
    ushort_t* w2h = (ushort_t*)(ws + O_W2H);
    ushort_t* w2l = (ushort_t*)(ws + O_W2L);
    ushort_t* hh  = (ushort_t*)(ws + O_HH);
    ushort_t* hl  = (ushort_t*)(ws + O_HL);

    // 1) split x + transpose/split W1
    prep2_kernel<<<2304, 256, 0, stream>>>(x, W1, xh, xl, w1h, w1l);
    // 2) gemm1 (fused bias+silu+split epilogue) co-scheduled with W2 transpose
    gemm1_w2t_kernel<<<8448, 256, 0, stream>>>(
        xh, xl, w1h, w1l, b1, hh, hl, W2, w2h, w2l);
    // 3) GEMM2: [256x2048] x [4096x2048]^T, 128m-tile, split-K=4
    gemm2k_kernel<<<dim3(64, 2, 4), 256, 0, stream>>>(hh, hl, w2h, w2l, part16);
    // 4) quantum (fused 4-way reduce + bias)
    quantum_kernel<<<256, 1024, 0, stream>>>(part16, b2, vp, Ao, Bo, Do, out, 1);
  } else {
    float* h     = (float*)d_ws;
    float* theta = h + 256 * 2048;
    gemm_tiled<<<dim3(32, 4), 256, 0, stream>>>(
        x, W1, b1, h, 256, 2047, 1024, 1024, 2047, 2048, 1, 2048);
    gemm_tiled<<<dim3(64, 4), 256, 0, stream>>>(
        h, W2, b2, theta, 256, 4095, 2047, 2048, 4095, 4096, 0, 4096);
    quantum_kernel<<<256, 1024, 0, stream>>>(theta, b2, vp, Ao, Bo, Do, out, 0);
  }
}